// Round 1
// baseline (165.176 us; speedup 1.0000x reference)
//
#include <hip/hip_runtime.h>
#include <math.h>

// ---------------------------------------------------------------------------
// HybridQuantumDQN: encoder MLP -> 8-qubit statevector sim -> decoder MLP.
// Design: one wave64 per sample; 256 amplitudes = 4 complex per lane in VGPRs.
//   amplitude index = lane*4 + t ; idx bit b: b in {0,1} = t bits, b in {2..7}
//   = lane bits 0..5. Wire w acts on bit (7-w)  (PennyLane: wire0 = MSB).
//   Wires 0..5: cross-lane via __shfl_xor(mask = 1<<(5-w)); wires 6,7 in-lane.
// Per layer: RY(enc)∘Rot fused into one complex 2x2 per qubit; CZ chain is a
// fixed ±1 sign per (lane,t) (precomputed once). Layer 0 built directly from
// gate column-0 products (state starts at |0...0>).
// Rot coefficients (sample-independent) precomputed by prep kernel into d_ws.
// ---------------------------------------------------------------------------

#define PI_F 3.14159265358979323846f

struct C2 { float re, im; };

// out = g*a + h*b   (complex 2-term dot)
__device__ __forceinline__ void cdot2(const C2& g, float ar, float ai,
                                      const C2& h, float br, float bi,
                                      float& outr, float& outi) {
    outr = fmaf(g.re, ar, fmaf(-g.im, ai, fmaf(h.re, br, -h.im * bi)));
    outi = fmaf(g.re, ai, fmaf( g.im, ar, fmaf(h.re, bi,  h.im * br)));
}

__device__ __forceinline__ C2 cmul(C2 a, C2 b) {
    C2 r;
    r.re = fmaf(a.re, b.re, -a.im * b.im);
    r.im = fmaf(a.re, b.im,  a.im * b.re);
    return r;
}

// Precompute Rot(phi,theta,omega) 2x2 complex coeffs per gate -> d_ws.
// layout per gate g: [g00.re g00.im g01.re g01.im g10.re g10.im g11.re g11.im]
__global__ void prep_rot(const float* __restrict__ qw, float* __restrict__ coef,
                         int n_gates) {
    int g = blockIdx.x * blockDim.x + threadIdx.x;
    if (g >= n_gates) return;
    float phi = qw[3 * g + 0], th = qw[3 * g + 1], om = qw[3 * g + 2];
    float c = cosf(0.5f * th), s = sinf(0.5f * th);
    float A = 0.5f * (phi + om), Bb = 0.5f * (phi - om);
    float cA = cosf(A), sA = sinf(A), cB = cosf(Bb), sB = sinf(Bb);
    float* o = coef + 8 * g;
    o[0] =  cA * c;  o[1] = -sA * c;   // g00 = e^{-iA} c
    o[2] = -cB * s;  o[3] = -sB * s;   // g01 = -e^{+iB} s
    o[4] =  cB * s;  o[5] = -sB * s;   // g10 = e^{-iB} s
    o[6] =  cA * c;  o[7] =  sA * c;   // g11 = e^{+iA} c
}

// Build fused G = Rot(l,q) @ RY(cq,sq)
__device__ __forceinline__ void load_G(const float* __restrict__ coef, int g,
                                       float cc, float ss,
                                       C2& G00, C2& G01, C2& G10, C2& G11) {
    const float4* cp = (const float4*)(coef + 8 * g);
    float4 c0 = cp[0];  // g00.re g00.im g01.re g01.im
    float4 c1 = cp[1];  // g10.re g10.im g11.re g11.im
    G00.re = fmaf(c0.x, cc,  c0.z * ss);  G00.im = fmaf(c0.y, cc,  c0.w * ss);
    G01.re = fmaf(c0.z, cc, -c0.x * ss);  G01.im = fmaf(c0.w, cc, -c0.y * ss);
    G10.re = fmaf(c1.x, cc,  c1.z * ss);  G10.im = fmaf(c1.y, cc,  c1.w * ss);
    G11.re = fmaf(c1.z, cc, -c1.x * ss);  G11.im = fmaf(c1.w, cc, -c1.y * ss);
}

// Apply complex 2x2 gate on wire q (0..7) to state (sr,si)[4].
__device__ __forceinline__ void apply_gate(int q, int lane,
                                           C2 G00, C2 G01, C2 G10, C2 G11,
                                           float sr[4], float si[4]) {
    if (q < 6) {
        int sh = 5 - q;
        int m = 1 << sh;
        bool hi = (lane >> sh) & 1;
        C2 cS = hi ? G11 : G00;
        C2 cO = hi ? G10 : G01;
#pragma unroll
        for (int t = 0; t < 4; t++) {
            float pr = __shfl_xor(sr[t], m, 64);
            float pi = __shfl_xor(si[t], m, 64);
            float nr, ni;
            cdot2(cS, sr[t], si[t], cO, pr, pi, nr, ni);
            sr[t] = nr; si[t] = ni;
        }
    } else if (q == 6) {  // bit1: pairs (0,2),(1,3)
#pragma unroll
        for (int p = 0; p < 2; p++) {
            float ar = sr[p], ai = si[p], br = sr[p + 2], bi = si[p + 2];
            cdot2(G00, ar, ai, G01, br, bi, sr[p], si[p]);
            cdot2(G10, ar, ai, G11, br, bi, sr[p + 2], si[p + 2]);
        }
    } else {  // q==7, bit0: pairs (0,1),(2,3)
#pragma unroll
        for (int p = 0; p < 2; p++) {
            int a = 2 * p, b = 2 * p + 1;
            float ar = sr[a], ai = si[a], br = sr[b], bi = si[b];
            cdot2(G00, ar, ai, G01, br, bi, sr[a], si[a]);
            cdot2(G10, ar, ai, G11, br, bi, sr[b], si[b]);
        }
    }
}

__global__ __launch_bounds__(256) void qdqn_kernel(
    const float* __restrict__ x,
    const float* __restrict__ ew1, const float* __restrict__ eb1,
    const float* __restrict__ ew2, const float* __restrict__ eb2,
    const float* __restrict__ coef,
    const float* __restrict__ dw1, const float* __restrict__ db1,
    const float* __restrict__ dw2, const float* __restrict__ db2,
    float* __restrict__ out, int B, int NL) {
    const int wid = blockIdx.x * (blockDim.x >> 6) + (threadIdx.x >> 6);
    const int lane = threadIdx.x & 63;
    if (wid >= B) return;

    // ---------------- encoder MLP (redundant across lanes; weights are
    // grid-uniform -> scalar loads) ----------------
    float xv[16];
    const float4* xp = (const float4*)(x + wid * 16);
#pragma unroll
    for (int i = 0; i < 4; i++) {
        float4 v = xp[i];
        xv[4 * i] = v.x; xv[4 * i + 1] = v.y; xv[4 * i + 2] = v.z; xv[4 * i + 3] = v.w;
    }
    float hbuf[8];
#pragma unroll
    for (int j = 0; j < 8; j++) {
        float a = eb1[j];
#pragma unroll
        for (int i = 0; i < 16; i++) a = fmaf(ew1[j * 16 + i], xv[i], a);
        hbuf[j] = fmaxf(a, 0.0f);
    }
    float cq[8], sq[8];
#pragma unroll
    for (int q = 0; q < 8; q++) {
        float a = eb2[q];
#pragma unroll
        for (int j = 0; j < 8; j++) a = fmaf(ew2[q * 8 + j], hbuf[j], a);
        float e = tanhf(a);
        float ang = e * (0.5f * PI_F);  // theta/2 with theta = enc*pi
        cq[q] = cosf(ang);
        sq[q] = sinf(ang);
    }

    // ---------------- CZ chain = fixed sign per (lane,t) ----------------
    int l0 = lane & 1, l1 = (lane >> 1) & 1, l2 = (lane >> 2) & 1;
    int l3 = (lane >> 3) & 1, l4 = (lane >> 4) & 1, l5 = (lane >> 5) & 1;
    int cnt = (l5 & l4) + (l4 & l3) + (l3 & l2) + (l2 & l1) + (l1 & l0);
    float s01 = (cnt & 1) ? -1.0f : 1.0f;
    float s2 = l0 ? -s01 : s01;
    float czs[4] = { s01, s01, s2, -s2 };

    // ---------------- layer 0: build product state directly ----------------
    float sr[4], si[4];
    {
        C2 P; P.re = 1.0f; P.im = 0.0f;
        C2 A60, A61, A70, A71;
#pragma unroll
        for (int q = 0; q < 8; q++) {
            C2 G00, G01, G10, G11;
            load_G(coef, q, cq[q], sq[q], G00, G01, G10, G11);
            if (q < 6) {
                int sh = 5 - q;
                bool hi = (lane >> sh) & 1;
                C2 f = hi ? G10 : G00;   // column 0 of G
                P = cmul(P, f);
            } else if (q == 6) { A60 = G00; A61 = G10; }
            else               { A70 = G00; A71 = G10; }
        }
        C2 T0 = cmul(A60, A70), T1 = cmul(A60, A71);
        C2 T2 = cmul(A61, A70), T3 = cmul(A61, A71);
        C2 TT[4] = { T0, T1, T2, T3 };
#pragma unroll
        for (int t = 0; t < 4; t++) {
            C2 a = cmul(P, TT[t]);
            sr[t] = a.re * czs[t];
            si[t] = a.im * czs[t];
        }
    }

    // ---------------- layers 1..NL-1 ----------------
    for (int l = 1; l < NL; l++) {
#pragma unroll
        for (int q = 0; q < 8; q++) {
            C2 G00, G01, G10, G11;
            load_G(coef, l * 8 + q, cq[q], sq[q], G00, G01, G10, G11);
            apply_gate(q, lane, G00, G01, G10, G11, sr, si);
        }
#pragma unroll
        for (int t = 0; t < 4; t++) { sr[t] *= czs[t]; si[t] *= czs[t]; }
    }

    // ---------------- final RY layer (real 2x2) ----------------
#pragma unroll
    for (int q = 0; q < 8; q++) {
        float c = cq[q], s = sq[q];
        if (q < 6) {
            int sh = 5 - q;
            int m = 1 << sh;
            bool hi = (lane >> sh) & 1;
            float cO = hi ? s : -s;
#pragma unroll
            for (int t = 0; t < 4; t++) {
                float pr = __shfl_xor(sr[t], m, 64);
                float pi = __shfl_xor(si[t], m, 64);
                sr[t] = fmaf(c, sr[t], cO * pr);
                si[t] = fmaf(c, si[t], cO * pi);
            }
        } else if (q == 6) {
#pragma unroll
            for (int p = 0; p < 2; p++) {
                float ar = sr[p], ai = si[p], br = sr[p + 2], bi = si[p + 2];
                sr[p]     = fmaf(c, ar, -s * br); si[p]     = fmaf(c, ai, -s * bi);
                sr[p + 2] = fmaf(s, ar,  c * br); si[p + 2] = fmaf(s, ai,  c * bi);
            }
        } else {
#pragma unroll
            for (int p = 0; p < 2; p++) {
                int a = 2 * p, b = 2 * p + 1;
                float ar = sr[a], ai = si[a], br = sr[b], bi = si[b];
                sr[a] = fmaf(c, ar, -s * br); si[a] = fmaf(c, ai, -s * bi);
                sr[b] = fmaf(s, ar,  c * br); si[b] = fmaf(s, ai,  c * bi);
            }
        }
    }

    // ---------------- probs -> <Z_w> ----------------
    float p0 = fmaf(sr[0], sr[0], si[0] * si[0]);
    float p1 = fmaf(sr[1], sr[1], si[1] * si[1]);
    float p2 = fmaf(sr[2], sr[2], si[2] * si[2]);
    float p3 = fmaf(sr[3], sr[3], si[3] * si[3]);
    float sumP = (p0 + p1) + (p2 + p3);
    float z[8];
#pragma unroll
    for (int w = 0; w < 6; w++) {
        int sh = 5 - w;
        z[w] = ((lane >> sh) & 1) ? -sumP : sumP;
    }
    z[6] = (p0 + p1) - (p2 + p3);
    z[7] = (p0 - p1) + (p2 - p3);
#pragma unroll
    for (int m = 1; m < 64; m <<= 1) {
#pragma unroll
        for (int w = 0; w < 8; w++) z[w] += __shfl_xor(z[w], m, 64);
    }

    // ---------------- decoder MLP ----------------
    float h2[8];
#pragma unroll
    for (int j = 0; j < 8; j++) {
        float a = db1[j];
#pragma unroll
        for (int w = 0; w < 8; w++) a = fmaf(dw1[j * 8 + w], z[w], a);
        h2[j] = fmaxf(a, 0.0f);
    }
    if (lane < 4) {
        float a = db2[lane];
#pragma unroll
        for (int j = 0; j < 8; j++) a = fmaf(dw2[lane * 8 + j], h2[j], a);
        out[wid * 4 + lane] = a;
    }
}

extern "C" void kernel_launch(void* const* d_in, const int* in_sizes, int n_in,
                              void* d_out, int out_size, void* d_ws, size_t ws_size,
                              hipStream_t stream) {
    const float* x   = (const float*)d_in[0];
    const float* ew1 = (const float*)d_in[1];
    const float* eb1 = (const float*)d_in[2];
    const float* ew2 = (const float*)d_in[3];
    const float* eb2 = (const float*)d_in[4];
    const float* qw  = (const float*)d_in[5];
    const float* dw1 = (const float*)d_in[6];
    const float* db1 = (const float*)d_in[7];
    const float* dw2 = (const float*)d_in[8];
    const float* db2 = (const float*)d_in[9];
    float* out  = (float*)d_out;
    float* coef = (float*)d_ws;  // n_gates*8 floats (1 KB) — rewritten every call

    int B = in_sizes[0] / 16;        // 32768
    int n_gates = in_sizes[5] / 3;   // NL*NQ = 32
    int NL = n_gates / 8;            // 4

    prep_rot<<<1, 64, 0, stream>>>(qw, coef, n_gates);

    int blocks = (B + 3) / 4;  // 4 waves (samples) per 256-thread block
    qdqn_kernel<<<blocks, 256, 0, stream>>>(x, ew1, eb1, ew2, eb2, coef,
                                            dw1, db1, dw2, db2, out, B, NL);
}

// Round 2
// 138.991 us; speedup vs baseline: 1.1884x; 1.1884x over previous
//
#include <hip/hip_runtime.h>
#include <math.h>

// ---------------------------------------------------------------------------
// HybridQuantumDQN: encoder MLP -> 8-qubit statevector sim -> decoder MLP.
// Round 2 layout: 4 samples per wave64. Each sample owns 16 lanes; each lane
// holds 16 complex amplitudes (32 VGPRs). amp index = L*16 + t where
// L = lane&15 (amp bits 7..4) and t in [0,16) (amp bits 3..0).
// Wire w acts on amp bit (7-w): wires 0..3 -> lane bits 3..0 (cross-lane,
// __shfl_xor mask 8/4/2/1 stays inside the 16-lane sample group);
// wires 4..7 -> t bits 3..0 (in-lane, no shuffles).
// Per layer: RY(enc)∘Rot fused into one complex 2x2 per qubit. CZ chain is a
// fixed ±1 per (L,t): two per-lane scalars (mL,mH) × compile-time t-signs.
// Layer 0 built directly as a product state (|0..0> input).
// Rot coefficients are sample-independent: computed once per block into LDS
// (no separate prep dispatch). Encoder/decoder amortized 4x across the wave.
// ---------------------------------------------------------------------------

#define PI_F 3.14159265358979323846f

struct C2 { float re, im; };

__device__ __forceinline__ C2 cmul(C2 a, C2 b) {
    C2 r;
    r.re = fmaf(a.re, b.re, -a.im * b.im);
    r.im = fmaf(a.re, b.im,  a.im * b.re);
    return r;
}

// (outr,outi) = g*(ar,ai) + h*(br,bi)
__device__ __forceinline__ void cdot2(const C2& g, float ar, float ai,
                                      const C2& h, float br, float bi,
                                      float& outr, float& outi) {
    outr = fmaf(g.re, ar, fmaf(-g.im, ai, fmaf(h.re, br, -h.im * bi)));
    outi = fmaf(g.re, ai, fmaf( g.im, ar, fmaf(h.re, bi,  h.im * br)));
}

// Build fused G = Rot(l,q) @ RY(cq,sq) from LDS coeffs
__device__ __forceinline__ void load_G(const float* __restrict__ c_lds, int g,
                                       float cc, float ss,
                                       C2& G00, C2& G01, C2& G10, C2& G11) {
    const float4* cp = (const float4*)(c_lds + 8 * g);
    float4 c0 = cp[0];  // g00.re g00.im g01.re g01.im
    float4 c1 = cp[1];  // g10.re g10.im g11.re g11.im
    G00.re = fmaf(c0.x, cc,  c0.z * ss);  G00.im = fmaf(c0.y, cc,  c0.w * ss);
    G01.re = fmaf(c0.z, cc, -c0.x * ss);  G01.im = fmaf(c0.w, cc, -c0.y * ss);
    G10.re = fmaf(c1.x, cc,  c1.z * ss);  G10.im = fmaf(c1.y, cc,  c1.w * ss);
    G11.re = fmaf(c1.z, cc, -c1.x * ss);  G11.im = fmaf(c1.w, cc, -c1.y * ss);
}

// Apply complex 2x2 gate on wire q (0..7). q is compile-time under unroll.
__device__ __forceinline__ void apply_gate16(int q, int lane,
                                             C2 G00, C2 G01, C2 G10, C2 G11,
                                             float sr[16], float si[16]) {
    if (q < 4) {               // cross-lane: lane bit (3-q)
        const int sh = 3 - q;
        const int m = 1 << sh;
        const bool hi = (lane >> sh) & 1;
        C2 cS = hi ? G11 : G00;
        C2 cO = hi ? G10 : G01;
#pragma unroll
        for (int t = 0; t < 16; t++) {
            float pr = __shfl_xor(sr[t], m, 64);
            float pi = __shfl_xor(si[t], m, 64);
            float nr, ni;
            cdot2(cS, sr[t], si[t], cO, pr, pi, nr, ni);
            sr[t] = nr; si[t] = ni;
        }
    } else {                   // in-lane: t bit (7-q)
        const int st = 1 << (7 - q);
#pragma unroll
        for (int t = 0; t < 16; t++) {
            if ((t & st) == 0) {
                const int u = t + st;
                float ar = sr[t], ai = si[t], br = sr[u], bi = si[u];
                cdot2(G00, ar, ai, G01, br, bi, sr[t], si[t]);
                cdot2(G10, ar, ai, G11, br, bi, sr[u], si[u]);
            }
        }
    }
}

// CZ t-part parity: (t3&t2)+(t2&t1)+(t1&t0) odd -> negate  (compile-time)
__device__ __constant__ const bool CZNEG[16] =
    { false,false,false,true,  false,false,true,false,
      false,false,false,true,  true, true, false,true };

__global__ __launch_bounds__(256) void qdqn_kernel(
    const float* __restrict__ x,
    const float* __restrict__ ew1, const float* __restrict__ eb1,
    const float* __restrict__ ew2, const float* __restrict__ eb2,
    const float* __restrict__ qw,
    const float* __restrict__ dw1, const float* __restrict__ db1,
    const float* __restrict__ dw2, const float* __restrict__ db2,
    float* __restrict__ out, int B, int NL) {
    __shared__ __align__(16) float c_lds[64 * 8];

    const int tid = threadIdx.x;
    const int n_gates = NL * 8;

    // ---- Rot coeffs once per block (gate g: 8 floats) ----
    if (tid < n_gates) {
        const int g = tid;
        float phi = qw[3 * g + 0], th = qw[3 * g + 1], om = qw[3 * g + 2];
        float c = __cosf(0.5f * th), s = __sinf(0.5f * th);
        float A = 0.5f * (phi + om), Bb = 0.5f * (phi - om);
        float cA = __cosf(A), sA = __sinf(A), cB = __cosf(Bb), sB = __sinf(Bb);
        float* o = c_lds + 8 * g;
        o[0] =  cA * c;  o[1] = -sA * c;   // g00 = e^{-iA} c
        o[2] = -cB * s;  o[3] = -sB * s;   // g01 = -e^{+iB} s
        o[4] =  cB * s;  o[5] = -sB * s;   // g10 = e^{-iB} s
        o[6] =  cA * c;  o[7] =  sA * c;   // g11 = e^{+iA} c
    }
    __syncthreads();

    const int wave = tid >> 6;
    const int lane = tid & 63;
    const int L = lane & 15;                       // amp bits 7..4
    int s = (blockIdx.x * 4 + wave) * 4 + (lane >> 4);
    if (s >= B) s = B - 1;                         // clamp (dup write same value)

    // ---------------- encoder MLP (redundant across the 16-lane group) -----
    float xv[16];
    const float4* xp = (const float4*)(x + s * 16);
#pragma unroll
    for (int i = 0; i < 4; i++) {
        float4 v = xp[i];
        xv[4*i] = v.x; xv[4*i+1] = v.y; xv[4*i+2] = v.z; xv[4*i+3] = v.w;
    }
    float hbuf[8];
#pragma unroll
    for (int j = 0; j < 8; j++) {
        float a = eb1[j];
#pragma unroll
        for (int i = 0; i < 16; i++) a = fmaf(ew1[j * 16 + i], xv[i], a);
        hbuf[j] = fmaxf(a, 0.0f);
    }
    float cq[8], sq[8];
#pragma unroll
    for (int q = 0; q < 8; q++) {
        float a = eb2[q];
#pragma unroll
        for (int j = 0; j < 8; j++) a = fmaf(ew2[q * 8 + j], hbuf[j], a);
        // tanh via native exp + fast rcp (robust at +-inf through rcp)
        float e = 1.0f - __fdividef(2.0f, __expf(2.0f * a) + 1.0f);
        float ang = e * (0.5f * PI_F);             // theta/2, |ang| <= pi/2
        cq[q] = __cosf(ang);
        sq[q] = __sinf(ang);
    }

    // ---------------- CZ chain: per-lane scalars ---------------------------
    // amp bits: [7:4]=L bits 3..0, [3:0]=t.  Adjacent-bit AND parity:
    // L-part: (L3&L2)+(L2&L1)+(L1&L0); cross term (L0 & t3); t-part in CZNEG.
    {
    }
    const int L0 = L & 1, L1b = (L >> 1) & 1, L2b = (L >> 2) & 1, L3b = (L >> 3) & 1;
    const int cnt = (L3b & L2b) + (L2b & L1b) + (L1b & L0);
    const float mL = (cnt & 1) ? -1.0f : 1.0f;     // multiplier for t < 8
    const float mH = L0 ? -mL : mL;                // t >= 8 adds (L0 & t3)

    // ---------------- layer 0: product state -------------------------------
    float sr[16], si[16];
    {
        C2 P; P.re = 1.0f; P.im = 0.0f;
        C2 F[4][2];                                // wires 4..7, rows 0/1, col 0
#pragma unroll
        for (int q = 0; q < 8; q++) {
            C2 G00, G01, G10, G11;
            load_G(c_lds, q, cq[q], sq[q], G00, G01, G10, G11);
            if (q < 4) {
                const int sh = 3 - q;
                const bool hi = (lane >> sh) & 1;
                C2 f = hi ? G10 : G00;
                P = cmul(P, f);
            } else {
                F[q - 4][0] = G00;                 // row 0 of column 0
                F[q - 4][1] = G10;                 // row 1 of column 0
            }
        }
        C2 A0 = cmul(P, F[0][0]), A1 = cmul(P, F[0][1]);   // t3
        C2 Bv[4];
        Bv[0] = cmul(A0, F[1][0]); Bv[1] = cmul(A0, F[1][1]);
        Bv[2] = cmul(A1, F[1][0]); Bv[3] = cmul(A1, F[1][1]);
        C2 Cv[8];
#pragma unroll
        for (int i = 0; i < 8; i++) Cv[i] = cmul(Bv[i >> 1], F[2][i & 1]);
#pragma unroll
        for (int t = 0; t < 16; t++) {
            C2 v = cmul(Cv[t >> 1], F[3][t & 1]);
            float m = (t < 8) ? mL : mH;
            m = CZNEG[t] ? -m : m;
            sr[t] = v.re * m;
            si[t] = v.im * m;
        }
    }

    // ---------------- layers 1..NL-1 ---------------------------------------
    for (int l = 1; l < NL; l++) {
#pragma unroll
        for (int q = 0; q < 8; q++) {
            C2 G00, G01, G10, G11;
            load_G(c_lds, l * 8 + q, cq[q], sq[q], G00, G01, G10, G11);
            apply_gate16(q, lane, G00, G01, G10, G11, sr, si);
        }
#pragma unroll
        for (int t = 0; t < 16; t++) {
            float m = (t < 8) ? mL : mH;
            m = CZNEG[t] ? -m : m;
            sr[t] *= m; si[t] *= m;
        }
    }

    // ---------------- final RY layer (real 2x2) ----------------------------
#pragma unroll
    for (int q = 0; q < 8; q++) {
        const float c = cq[q], sv = sq[q];
        if (q < 4) {
            const int sh = 3 - q;
            const int m = 1 << sh;
            const bool hi = (lane >> sh) & 1;
            const float cO = hi ? sv : -sv;
#pragma unroll
            for (int t = 0; t < 16; t++) {
                float pr = __shfl_xor(sr[t], m, 64);
                float pi = __shfl_xor(si[t], m, 64);
                sr[t] = fmaf(c, sr[t], cO * pr);
                si[t] = fmaf(c, si[t], cO * pi);
            }
        } else {
            const int st = 1 << (7 - q);
#pragma unroll
            for (int t = 0; t < 16; t++) {
                if ((t & st) == 0) {
                    const int u = t + st;
                    float ar = sr[t], ai = si[t], br = sr[u], bi = si[u];
                    sr[t] = fmaf(c, ar, -sv * br); si[t] = fmaf(c, ai, -sv * bi);
                    sr[u] = fmaf(sv, ar,  c * br); si[u] = fmaf(sv, ai,  c * bi);
                }
            }
        }
    }

    // ---------------- probs -> <Z_w> ---------------------------------------
    float p[16];
#pragma unroll
    for (int t = 0; t < 16; t++) p[t] = fmaf(sr[t], sr[t], si[t] * si[t]);

    float e0 = p[0]+p[1],  e1 = p[2]+p[3],  e2 = p[4]+p[5],  e3 = p[6]+p[7];
    float e4 = p[8]+p[9],  e5 = p[10]+p[11], e6 = p[12]+p[13], e7 = p[14]+p[15];
    float q0 = e0+e1, q1 = e2+e3, q2 = e4+e5, q3 = e6+e7;
    float h0 = q0+q1, h1 = q2+q3;
    float sumP = h0 + h1;

    float z[8];
#pragma unroll
    for (int w = 0; w < 4; w++)                        // wires 0..3: lane bits
        z[w] = ((L >> (3 - w)) & 1) ? -sumP : sumP;
    z[4] = h0 - h1;                                    // t3
    z[5] = (q0 - q1) + (q2 - q3);                      // t2
    z[6] = (e0 - e1) + (e2 - e3) + (e4 - e5) + (e6 - e7);   // t1
    z[7] = (p[0]-p[1]) + (p[2]-p[3]) + (p[4]-p[5]) + (p[6]-p[7])
         + (p[8]-p[9]) + (p[10]-p[11]) + (p[12]-p[13]) + (p[14]-p[15]); // t0

    // reduce across the 16-lane sample group
#pragma unroll
    for (int m = 1; m < 16; m <<= 1) {
#pragma unroll
        for (int w = 0; w < 8; w++) z[w] += __shfl_xor(z[w], m, 64);
    }

    // ---------------- decoder MLP ------------------------------------------
    float h2[8];
#pragma unroll
    for (int j = 0; j < 8; j++) {
        float a = db1[j];
#pragma unroll
        for (int w = 0; w < 8; w++) a = fmaf(dw1[j * 8 + w], z[w], a);
        h2[j] = fmaxf(a, 0.0f);
    }
    if (L < 4) {
        float a = db2[L];
#pragma unroll
        for (int j = 0; j < 8; j++) a = fmaf(dw2[L * 8 + j], h2[j], a);
        out[s * 4 + L] = a;
    }
}

extern "C" void kernel_launch(void* const* d_in, const int* in_sizes, int n_in,
                              void* d_out, int out_size, void* d_ws, size_t ws_size,
                              hipStream_t stream) {
    const float* x   = (const float*)d_in[0];
    const float* ew1 = (const float*)d_in[1];
    const float* eb1 = (const float*)d_in[2];
    const float* ew2 = (const float*)d_in[3];
    const float* eb2 = (const float*)d_in[4];
    const float* qw  = (const float*)d_in[5];
    const float* dw1 = (const float*)d_in[6];
    const float* db1 = (const float*)d_in[7];
    const float* dw2 = (const float*)d_in[8];
    const float* db2 = (const float*)d_in[9];
    float* out = (float*)d_out;

    int B = in_sizes[0] / 16;        // 32768
    int n_gates = in_sizes[5] / 3;   // NL*NQ = 32
    int NL = n_gates / 8;            // 4

    // 16 samples per 256-thread block (4 waves x 4 samples/wave)
    int blocks = (B + 15) / 16;
    qdqn_kernel<<<blocks, 256, 0, stream>>>(x, ew1, eb1, ew2, eb2, qw,
                                            dw1, db1, dw2, db2, out, B, NL);
}

// Round 3
// 137.065 us; speedup vs baseline: 1.2051x; 1.0141x over previous
//
#include <hip/hip_runtime.h>
#include <math.h>

// ---------------------------------------------------------------------------
// HybridQuantumDQN: encoder MLP -> 8-qubit statevector sim -> decoder MLP.
// Round 3: same math as round 2 (4 samples/wave64; 16 lanes/sample; 16 complex
// amps/lane; wires 0-3 cross-lane xor{8,4,2,1}, wires 4-7 in-lane), plus:
//  - cross-lane exchanges via DPP (quad_perm for xor1/2, row_ror:8 for xor8)
//    instead of LDS shuffles; only xor4 uses ds_swizzle. Kills DS-pipe stalls.
//  - SU(2) gate form: fused RY(enc)∘Rot = [[a,-conj(b)],[b,conj(a)]]; build
//    only (a,b) (8 fma) and get row selects via precomputed per-lane sign
//    masks (2 v_xor) instead of cndmasks.
//  - 64-thread (1-wave) blocks: fine-grained load balance (round 2's 256-thr
//    blocks hit a 6-of-8-blocks/CU capacity cliff -> 28% occupancy).
// ---------------------------------------------------------------------------

#define PI_F 3.14159265358979323846f

struct C2 { float re, im; };

__device__ __forceinline__ C2 cmul(C2 a, C2 b) {
    C2 r;
    r.re = fmaf(a.re, b.re, -a.im * b.im);
    r.im = fmaf(a.re, b.im,  a.im * b.re);
    return r;
}

__device__ __forceinline__ float fxor(float x, int m) {
    return __int_as_float(__float_as_int(x) ^ m);
}

// ---- cross-lane xor exchange: DPP where possible, ds_swizzle for xor4 ----
template<int CTRL>
__device__ __forceinline__ float dppf(float x) {
    int xi = __float_as_int(x);
    int r = __builtin_amdgcn_update_dpp(xi, xi, CTRL, 0xF, 0xF, false);
    return __int_as_float(r);
}
__device__ __forceinline__ float swz4(float x) {
    // BitMode: and=0x1F, or=0, xor=4 -> lane ^ 4
    return __int_as_float(__builtin_amdgcn_ds_swizzle(__float_as_int(x), 0x101F));
}
template<int M>
__device__ __forceinline__ float lxor(float x) {
    if constexpr (M == 1)      return dppf<0xB1>(x);   // quad_perm [1,0,3,2]
    else if constexpr (M == 2) return dppf<0x4E>(x);   // quad_perm [2,3,0,1]
    else if constexpr (M == 4) return swz4(x);         // ds_swizzle lane^4
    else                       return dppf<0x128>(x);  // row_ror:8 == lane^8 in row16
}

// ---- gate application ----
// cross-lane: new = cS*self + cO*partner, cS/cO already sign-adjusted per lane
template<int M>
__device__ __forceinline__ void cross_gate(float cSr, float cSi, float cOr, float cOi,
                                           float sr[16], float si[16]) {
#pragma unroll
    for (int t = 0; t < 16; t++) {
        float pr = lxor<M>(sr[t]);
        float pi = lxor<M>(si[t]);
        float nr = fmaf(cSr, sr[t], fmaf(-cSi, si[t], fmaf(cOr, pr, -cOi * pi)));
        float ni = fmaf(cSr, si[t], fmaf( cSi, sr[t], fmaf(cOr, pi,  cOi * pr)));
        sr[t] = nr; si[t] = ni;
    }
}

// in-lane SU(2) gate on t-bit ST:  [x,y] -> [a*x - conj(b)*y, b*x + conj(a)*y]
template<int ST>
__device__ __forceinline__ void inlane_gate(float ar, float ai, float br, float bi,
                                            float sr[16], float si[16]) {
#pragma unroll
    for (int t = 0; t < 16; t++) {
        if ((t & ST) == 0) {
            const int u = t + ST;
            float xr = sr[t], xi = si[t], yr = sr[u], yi = si[u];
            sr[t] = fmaf(ar, xr, fmaf(-ai, xi, fmaf(-br, yr, -bi * yi)));
            si[t] = fmaf(ar, xi, fmaf( ai, xr, fmaf(-br, yi,  bi * yr)));
            sr[u] = fmaf(br, xr, fmaf(-bi, xi, fmaf( ar, yr,  ai * yi)));
            si[u] = fmaf(br, xi, fmaf( bi, xr, fmaf( ar, yi, -ai * yr)));
        }
    }
}

// final RY (real): cO pre-signed per lane (-s on lo lanes, +s on hi lanes)
template<int M>
__device__ __forceinline__ void cross_ry(float c, float cO, float sr[16], float si[16]) {
#pragma unroll
    for (int t = 0; t < 16; t++) {
        float pr = lxor<M>(sr[t]);
        float pi = lxor<M>(si[t]);
        sr[t] = fmaf(c, sr[t], cO * pr);
        si[t] = fmaf(c, si[t], cO * pi);
    }
}
template<int ST>
__device__ __forceinline__ void inlane_ry(float c, float s, float sr[16], float si[16]) {
#pragma unroll
    for (int t = 0; t < 16; t++) {
        if ((t & ST) == 0) {
            const int u = t + ST;
            float xr = sr[t], xi = si[t], yr = sr[u], yi = si[u];
            sr[t] = fmaf(c, xr, -s * yr); si[t] = fmaf(c, xi, -s * yi);
            sr[u] = fmaf(s, xr,  c * yr); si[u] = fmaf(s, xi,  c * yi);
        }
    }
}

// Build fused SU(2) gate G = Rot * RY(cc,ss): a' = aR*cc - conj(bR)*ss ... etc.
__device__ __forceinline__ void load_G2(const float* __restrict__ c_lds, int g,
                                        float cc, float ss,
                                        float& ar, float& ai, float& br, float& bi) {
    const float4 c0 = *(const float4*)(c_lds + 4 * g);  // aR.re aR.im bR.re bR.im
    ar = fmaf(c0.x, cc, -c0.z * ss);
    ai = fmaf(c0.y, cc,  c0.w * ss);
    br = fmaf(c0.z, cc,  c0.x * ss);
    bi = fmaf(c0.w, cc, -c0.y * ss);
}

__global__ __launch_bounds__(64) void qdqn_kernel(
    const float* __restrict__ x,
    const float* __restrict__ ew1, const float* __restrict__ eb1,
    const float* __restrict__ ew2, const float* __restrict__ eb2,
    const float* __restrict__ qw,
    const float* __restrict__ dw1, const float* __restrict__ db1,
    const float* __restrict__ dw2, const float* __restrict__ db2,
    float* __restrict__ out, int B, int NL) {
    __shared__ __align__(16) float c_lds[32 * 4];

    const int lane = threadIdx.x;
    const int n_gates = NL * 8;

    // ---- Rot SU(2) coeffs once per block: a = e^{-iA}c, b = e^{-iB}s ----
    if (lane < n_gates) {
        const int g = lane;
        float phi = qw[3 * g + 0], th = qw[3 * g + 1], om = qw[3 * g + 2];
        float c = __cosf(0.5f * th), s = __sinf(0.5f * th);
        float A = 0.5f * (phi + om), Bb = 0.5f * (phi - om);
        float* o = c_lds + 4 * g;
        o[0] =  __cosf(A) * c;  o[1] = -__sinf(A) * c;
        o[2] =  __cosf(Bb) * s; o[3] = -__sinf(Bb) * s;
    }
    __syncthreads();

    const int L = lane & 15;                       // amp bits 7..4
    int s = blockIdx.x * 4 + (lane >> 4);
    if (s >= B) s = B - 1;

    // ---------------- encoder MLP ----------------
    float xv[16];
    const float4* xp = (const float4*)(x + s * 16);
#pragma unroll
    for (int i = 0; i < 4; i++) {
        float4 v = xp[i];
        xv[4*i] = v.x; xv[4*i+1] = v.y; xv[4*i+2] = v.z; xv[4*i+3] = v.w;
    }
    float hbuf[8];
#pragma unroll
    for (int j = 0; j < 8; j++) {
        float a = eb1[j];
#pragma unroll
        for (int i = 0; i < 16; i++) a = fmaf(ew1[j * 16 + i], xv[i], a);
        hbuf[j] = fmaxf(a, 0.0f);
    }
    float cq[8], sq[8];
#pragma unroll
    for (int q = 0; q < 8; q++) {
        float a = eb2[q];
#pragma unroll
        for (int j = 0; j < 8; j++) a = fmaf(ew2[q * 8 + j], hbuf[j], a);
        float e = 1.0f - __fdividef(2.0f, __expf(2.0f * a) + 1.0f);  // tanh
        float ang = e * (0.5f * PI_F);
        cq[q] = __cosf(ang);
        sq[q] = __sinf(ang);
    }

    // ---- per-lane sign masks for cross wires q=0..3 (bit 3-q of L) ----
    // lo lane: cS=(ar,ai)      cO=(-br,bi)   (row0: a, -conj(b))
    // hi lane: cS=(ar,-ai)     cO=( br,bi)   (row1 swap: conj(a), b)
    int hiM[4], loM[4];
#pragma unroll
    for (int q = 0; q < 4; q++) {
        int hi = (L >> (3 - q)) & 1;
        hiM[q] = hi << 31;                 // flips ai when hi
        loM[q] = hiM[q] ^ 0x80000000;      // flips br when lo
    }

    // ---- CZ chain signs ----
    const int L0 = L & 1, L1b = (L >> 1) & 1, L2b = (L >> 2) & 1, L3b = (L >> 3) & 1;
    const int cnt = (L3b & L2b) + (L2b & L1b) + (L1b & L0);
    const float mL = (cnt & 1) ? -1.0f : 1.0f;     // t < 8
    const float mH = L0 ? -mL : mL;                // t >= 8 adds (L0 & t3)
    constexpr bool CZNEG[16] =
        { false,false,false,true,  false,false,true,false,
          false,false,false,true,  true, true, false,true };

    // ---------------- layer 0: product state ----------------
    float sr[16], si[16];
    {
        C2 P; P.re = 1.0f; P.im = 0.0f;
        C2 F[4][2];
#pragma unroll
        for (int q = 0; q < 8; q++) {
            float ar, ai, br, bi;
            load_G2(c_lds, q, cq[q], sq[q], ar, ai, br, bi);
            if (q < 4) {
                const bool hi = (L >> (3 - q)) & 1;
                C2 f; f.re = hi ? br : ar; f.im = hi ? bi : ai;  // column 0
                P = cmul(P, f);
            } else {
                F[q-4][0].re = ar; F[q-4][0].im = ai;            // row0 col0
                F[q-4][1].re = br; F[q-4][1].im = bi;            // row1 col0
            }
        }
        C2 A0 = cmul(P, F[0][0]), A1 = cmul(P, F[0][1]);
        C2 Bv[4];
        Bv[0] = cmul(A0, F[1][0]); Bv[1] = cmul(A0, F[1][1]);
        Bv[2] = cmul(A1, F[1][0]); Bv[3] = cmul(A1, F[1][1]);
        C2 Cv[8];
#pragma unroll
        for (int i = 0; i < 8; i++) Cv[i] = cmul(Bv[i >> 1], F[2][i & 1]);
#pragma unroll
        for (int t = 0; t < 16; t++) {
            C2 v = cmul(Cv[t >> 1], F[3][t & 1]);
            float m = (t < 8) ? mL : mH;
            m = CZNEG[t] ? -m : m;
            sr[t] = v.re * m;
            si[t] = v.im * m;
        }
    }

    // ---------------- layers 1..NL-1 ----------------
    for (int l = 1; l < NL; l++) {
        const int g0 = l * 8;
        float ar, ai, br, bi;
        load_G2(c_lds, g0 + 0, cq[0], sq[0], ar, ai, br, bi);
        cross_gate<8>(ar, fxor(ai, hiM[0]), fxor(br, loM[0]), bi, sr, si);
        load_G2(c_lds, g0 + 1, cq[1], sq[1], ar, ai, br, bi);
        cross_gate<4>(ar, fxor(ai, hiM[1]), fxor(br, loM[1]), bi, sr, si);
        load_G2(c_lds, g0 + 2, cq[2], sq[2], ar, ai, br, bi);
        cross_gate<2>(ar, fxor(ai, hiM[2]), fxor(br, loM[2]), bi, sr, si);
        load_G2(c_lds, g0 + 3, cq[3], sq[3], ar, ai, br, bi);
        cross_gate<1>(ar, fxor(ai, hiM[3]), fxor(br, loM[3]), bi, sr, si);
        load_G2(c_lds, g0 + 4, cq[4], sq[4], ar, ai, br, bi);
        inlane_gate<8>(ar, ai, br, bi, sr, si);
        load_G2(c_lds, g0 + 5, cq[5], sq[5], ar, ai, br, bi);
        inlane_gate<4>(ar, ai, br, bi, sr, si);
        load_G2(c_lds, g0 + 6, cq[6], sq[6], ar, ai, br, bi);
        inlane_gate<2>(ar, ai, br, bi, sr, si);
        load_G2(c_lds, g0 + 7, cq[7], sq[7], ar, ai, br, bi);
        inlane_gate<1>(ar, ai, br, bi, sr, si);
#pragma unroll
        for (int t = 0; t < 16; t++) {
            float m = (t < 8) ? mL : mH;
            m = CZNEG[t] ? -m : m;
            sr[t] *= m; si[t] *= m;
        }
    }

    // ---------------- final RY layer ----------------
    cross_ry<8>(cq[0], fxor(sq[0], loM[0]), sr, si);
    cross_ry<4>(cq[1], fxor(sq[1], loM[1]), sr, si);
    cross_ry<2>(cq[2], fxor(sq[2], loM[2]), sr, si);
    cross_ry<1>(cq[3], fxor(sq[3], loM[3]), sr, si);
    inlane_ry<8>(cq[4], sq[4], sr, si);
    inlane_ry<4>(cq[5], sq[5], sr, si);
    inlane_ry<2>(cq[6], sq[6], sr, si);
    inlane_ry<1>(cq[7], sq[7], sr, si);

    // ---------------- probs -> <Z_w> ----------------
    float p[16];
#pragma unroll
    for (int t = 0; t < 16; t++) p[t] = fmaf(sr[t], sr[t], si[t] * si[t]);

    float e0 = p[0]+p[1],  e1 = p[2]+p[3],  e2 = p[4]+p[5],  e3 = p[6]+p[7];
    float e4 = p[8]+p[9],  e5 = p[10]+p[11], e6 = p[12]+p[13], e7 = p[14]+p[15];
    float q0 = e0+e1, q1 = e2+e3, q2 = e4+e5, q3 = e6+e7;
    float h0 = q0+q1, h1 = q2+q3;
    float sumP = h0 + h1;

    float z[8];
#pragma unroll
    for (int w = 0; w < 4; w++)
        z[w] = ((L >> (3 - w)) & 1) ? -sumP : sumP;
    z[4] = h0 - h1;
    z[5] = (q0 - q1) + (q2 - q3);
    z[6] = (e0 - e1) + (e2 - e3) + (e4 - e5) + (e6 - e7);
    z[7] = (p[0]-p[1]) + (p[2]-p[3]) + (p[4]-p[5]) + (p[6]-p[7])
         + (p[8]-p[9]) + (p[10]-p[11]) + (p[12]-p[13]) + (p[14]-p[15]);

#pragma unroll
    for (int w = 0; w < 8; w++) z[w] += lxor<1>(z[w]);
#pragma unroll
    for (int w = 0; w < 8; w++) z[w] += lxor<2>(z[w]);
#pragma unroll
    for (int w = 0; w < 8; w++) z[w] += lxor<4>(z[w]);
#pragma unroll
    for (int w = 0; w < 8; w++) z[w] += lxor<8>(z[w]);

    // ---------------- decoder MLP ----------------
    float h2[8];
#pragma unroll
    for (int j = 0; j < 8; j++) {
        float a = db1[j];
#pragma unroll
        for (int w = 0; w < 8; w++) a = fmaf(dw1[j * 8 + w], z[w], a);
        h2[j] = fmaxf(a, 0.0f);
    }
    if (L < 4) {
        float a = db2[L];
#pragma unroll
        for (int j = 0; j < 8; j++) a = fmaf(dw2[L * 8 + j], h2[j], a);
        out[s * 4 + L] = a;
    }
}

extern "C" void kernel_launch(void* const* d_in, const int* in_sizes, int n_in,
                              void* d_out, int out_size, void* d_ws, size_t ws_size,
                              hipStream_t stream) {
    const float* x   = (const float*)d_in[0];
    const float* ew1 = (const float*)d_in[1];
    const float* eb1 = (const float*)d_in[2];
    const float* ew2 = (const float*)d_in[3];
    const float* eb2 = (const float*)d_in[4];
    const float* qw  = (const float*)d_in[5];
    const float* dw1 = (const float*)d_in[6];
    const float* db1 = (const float*)d_in[7];
    const float* dw2 = (const float*)d_in[8];
    const float* db2 = (const float*)d_in[9];
    float* out = (float*)d_out;

    int B = in_sizes[0] / 16;        // 32768
    int n_gates = in_sizes[5] / 3;   // 32
    int NL = n_gates / 8;            // 4

    // 1-wave blocks, 4 samples each: fine-grained load balance across CUs
    int blocks = (B + 3) / 4;
    qdqn_kernel<<<blocks, 64, 0, stream>>>(x, ew1, eb1, ew2, eb2, qw,
                                           dw1, db1, dw2, db2, out, B, NL);
}

// Round 4
// 121.599 us; speedup vs baseline: 1.3584x; 1.1272x over previous
//
#include <hip/hip_runtime.h>
#include <math.h>

// ---------------------------------------------------------------------------
// HybridQuantumDQN: encoder MLP -> 8-qubit statevector sim -> decoder MLP.
// Round 4: issue-slot-bound -> packed fp32 (VOP3P v_pk_fma_f32) everywhere in
// the gate loops. Layout: 4 samples/wave64, 16 lanes/sample, 16 complex amps
// per lane stored as float2 (v2f) = 32 VGPRs.
//   Layout A: amp = L*16 + t  (L = lane&15 -> amp bits 7..4, t = reg idx).
//   Layout B: amp = j*16 + L  (j = reg idx -> amp bits 7..4).
// All single-qubit gates of a layer commute -> apply the 4 in-lane wires,
// transpose A<->B through LDS (wave-local, padded stride 18 rows), apply the
// other 4 wires in-lane. Every gate is a uniform-coefficient in-lane SU(2)
// pair update = 8 pk instructions (vs 16 scalar fma). CZ chain is a ±1
// diagonal with closed form in both layouts. 2-wave (128-thr) blocks.
// ---------------------------------------------------------------------------

#define PI_F 3.14159265358979323846f

typedef float v2f __attribute__((ext_vector_type(2)));

struct C2 { float re, im; };
__device__ __forceinline__ C2 cmul(C2 a, C2 b) {
    C2 r;
    r.re = fmaf(a.re, b.re, -a.im * b.im);
    r.im = fmaf(a.re, b.im,  a.im * b.re);
    return r;
}

// ---------------- packed fp32 primitives (VOP3P) ----------------
__device__ __forceinline__ v2f pk_mul(v2f a, v2f b) {
    v2f d; asm("v_pk_mul_f32 %0, %1, %2" : "=v"(d) : "v"(a), "v"(b)); return d;
}
// d = -(a*b)   (both halves)
__device__ __forceinline__ v2f pk_mul_neg(v2f a, v2f b) {
    v2f d; asm("v_pk_mul_f32 %0, %1, %2 neg_lo:[1,0] neg_hi:[1,0]"
               : "=v"(d) : "v"(a), "v"(b)); return d;
}
__device__ __forceinline__ v2f pk_fma(v2f a, v2f b, v2f c) {
    v2f d; asm("v_pk_fma_f32 %0, %1, %2, %3" : "=v"(d) : "v"(a), "v"(b), "v"(c)); return d;
}
// d = -(a*b) + c  (both halves)
__device__ __forceinline__ v2f pk_fma_nn(v2f a, v2f b, v2f c) {
    v2f d; asm("v_pk_fma_f32 %0, %1, %2, %3 neg_lo:[1,0,0] neg_hi:[1,0,0]"
               : "=v"(d) : "v"(a), "v"(b), "v"(c)); return d;
}
// d.lo = -a.lo*b.hi + c.lo ; d.hi = a.hi*b.lo + c.hi   (complex cross term)
__device__ __forceinline__ v2f pk_fma_swl(v2f a, v2f b, v2f c) {
    v2f d; asm("v_pk_fma_f32 %0, %1, %2, %3 op_sel:[0,1,0] op_sel_hi:[1,0,1] neg_lo:[1,0,0]"
               : "=v"(d) : "v"(a), "v"(b), "v"(c)); return d;
}
// d.lo = a.lo*b.hi + c.lo ; d.hi = -a.hi*b.lo + c.hi
__device__ __forceinline__ v2f pk_fma_swh(v2f a, v2f b, v2f c) {
    v2f d; asm("v_pk_fma_f32 %0, %1, %2, %3 op_sel:[0,1,0] op_sel_hi:[1,0,1] neg_hi:[1,0,0]"
               : "=v"(d) : "v"(a), "v"(b), "v"(c)); return d;
}

// ---------------- cross-lane (expval reduce only) ----------------
template<int CTRL>
__device__ __forceinline__ float dppf(float x) {
    int xi = __float_as_int(x);
    int r = __builtin_amdgcn_update_dpp(xi, xi, CTRL, 0xF, 0xF, false);
    return __int_as_float(r);
}
template<int M>
__device__ __forceinline__ float lxor(float x) {
    if constexpr (M == 1)      return dppf<0xB1>(x);   // quad_perm [1,0,3,2]
    else if constexpr (M == 2) return dppf<0x4E>(x);   // quad_perm [2,3,0,1]
    else if constexpr (M == 4) return __int_as_float(
        __builtin_amdgcn_ds_swizzle(__float_as_int(x), 0x101F));  // lane^4
    else                       return dppf<0x128>(x);  // row_ror:8 == lane^8
}

// ---------------- gates ----------------
// fused SU(2) gate G = Rot * RY: columns (a,b); G = [[a,-conj(b)],[b,conj(a)]]
__device__ __forceinline__ void build_G(const float* __restrict__ c_lds, int g,
                                        float cc, float ss,
                                        v2f& arr, v2f& aii, v2f& brr, v2f& bii) {
    const float4 c0 = *(const float4*)(c_lds + 4 * g);  // aR.re aR.im bR.re bR.im
    float ar = fmaf(c0.x, cc, -c0.z * ss);
    float ai = fmaf(c0.y, cc,  c0.w * ss);
    float br = fmaf(c0.z, cc,  c0.x * ss);
    float bi = fmaf(c0.w, cc, -c0.y * ss);
    arr = (v2f){ar, ar}; aii = (v2f){ai, ai};
    brr = (v2f){br, br}; bii = (v2f){bi, bi};
}

// in-lane SU(2) on register-index bit ST: 8 pk per pair
template<int ST>
__device__ __forceinline__ void su2_inlane(v2f arr, v2f aii, v2f brr, v2f bii,
                                           v2f z[16]) {
#pragma unroll
    for (int t = 0; t < 16; t++) {
        if ((t & ST) == 0) {
            const int u = t + ST;
            v2f x = z[t], y = z[u];
            v2f nx = pk_mul(arr, x);         // ( ar xr,  ar xi)
            nx = pk_fma_swl(aii, x, nx);     // (-ai xi, +ai xr)
            nx = pk_fma_nn (brr, y, nx);     // (-br yr, -br yi)
            nx = pk_fma_swl(bii, y, nx);     // (-bi yi, +bi yr)
            v2f ny = pk_mul(brr, x);         // ( br xr,  br xi)
            ny = pk_fma_swl(bii, x, ny);     // (-bi xi, +bi xr)
            ny = pk_fma   (arr, y, ny);      // (+ar yr, +ar yi)
            ny = pk_fma_swh(aii, y, ny);     // (+ai yi, -ai yr)
            z[t] = nx; z[u] = ny;
        }
    }
}

// in-lane real RY: 4 pk per pair
template<int ST>
__device__ __forceinline__ void ry_inlane(v2f cc, v2f ss, v2f z[16]) {
#pragma unroll
    for (int t = 0; t < 16; t++) {
        if ((t & ST) == 0) {
            const int u = t + ST;
            v2f x = z[t], y = z[u];
            z[t] = pk_fma_nn(ss, y, pk_mul(cc, x));   // c*x - s*y
            z[u] = pk_fma   (cc, y, pk_mul(ss, x));   // s*x + c*y
        }
    }
}

// parity of adjacent-1 pairs within a 4-bit value (CZ building block)
__device__ __constant__ const bool CZNEG[16] =
    { false,false,false,true,  false,false,true,false,
      false,false,false,true,  true, true, false,true };

__global__ __launch_bounds__(128) void qdqn_kernel(
    const float* __restrict__ x,
    const float* __restrict__ ew1, const float* __restrict__ eb1,
    const float* __restrict__ ew2, const float* __restrict__ eb2,
    const float* __restrict__ qw,
    const float* __restrict__ dw1, const float* __restrict__ db1,
    const float* __restrict__ dw2, const float* __restrict__ db2,
    float* __restrict__ out, int B, int NL) {
    __shared__ __align__(16) float c_lds[32 * 4];
    __shared__ __align__(16) v2f tbuf[2 * 4 * 288];   // 2 waves x 4 groups x 16x18

    const int tid = threadIdx.x;
    const int n_gates = NL * 8;

    // ---- Rot SU(2) coeffs once per block: a = e^{-iA}c, b = e^{-iB}s ----
    if (tid < n_gates) {
        const int g = tid;
        float phi = qw[3 * g + 0], th = qw[3 * g + 1], om = qw[3 * g + 2];
        float c = __cosf(0.5f * th), s = __sinf(0.5f * th);
        float A = 0.5f * (phi + om), Bb = 0.5f * (phi - om);
        float* o = c_lds + 4 * g;
        o[0] =  __cosf(A) * c;  o[1] = -__sinf(A) * c;
        o[2] =  __cosf(Bb) * s; o[3] = -__sinf(Bb) * s;
    }
    __syncthreads();

    const int wave = tid >> 6;
    const int lane = tid & 63;
    const int grp = lane >> 4;
    const int L = lane & 15;
    int s = blockIdx.x * 8 + wave * 4 + grp;
    if (s >= B) s = B - 1;
    v2f* tb = &tbuf[(wave * 4 + grp) * 288];

    // ---------------- encoder MLP ----------------
    float xv[16];
    const float4* xp = (const float4*)(x + s * 16);
#pragma unroll
    for (int i = 0; i < 4; i++) {
        float4 v = xp[i];
        xv[4*i] = v.x; xv[4*i+1] = v.y; xv[4*i+2] = v.z; xv[4*i+3] = v.w;
    }
    float hbuf[8];
#pragma unroll
    for (int j = 0; j < 8; j++) {
        float a = eb1[j];
#pragma unroll
        for (int i = 0; i < 16; i++) a = fmaf(ew1[j * 16 + i], xv[i], a);
        hbuf[j] = fmaxf(a, 0.0f);
    }
    float cq[8], sq[8];
#pragma unroll
    for (int q = 0; q < 8; q++) {
        float a = eb2[q];
#pragma unroll
        for (int j = 0; j < 8; j++) a = fmaf(ew2[q * 8 + j], hbuf[j], a);
        float e = 1.0f - __fdividef(2.0f, __expf(2.0f * a) + 1.0f);  // tanh
        float ang = e * (0.5f * PI_F);
        cq[q] = __cosf(ang);
        sq[q] = __sinf(ang);
    }

    // ---- CZ lane scalars ----
    // amp = (hi<<4)|lo; sign = parity(pairs(hi) + (hi0 & lo3) + pairs(lo)).
    // Layout A: hi=L(lane), lo=t(reg): per-reg m = (t<8 ? mL : mH) * CZNEG[t].
    // Layout B: hi=j(reg), lo=L(lane): per-reg m = (j&1 ? mO : mL) * CZNEG[j].
    const int L0 = L & 1, L1b = (L >> 1) & 1, L2b = (L >> 2) & 1, L3b = (L >> 3) & 1;
    const int cnt = (L3b & L2b) + (L2b & L1b) + (L1b & L0);
    const float mL = (cnt & 1) ? -1.0f : 1.0f;
    const float mH = L0 ? -mL : mL;
    const float mO = L3b ? -mL : mL;
    const v2f mL2 = (v2f){mL, mL}, mH2 = (v2f){mH, mH}, mO2 = (v2f){mO, mO};

    // ---------------- layer 0: product state (layout A), CZ folded --------
    v2f z[16];
    {
        C2 P; P.re = 1.0f; P.im = 0.0f;
        C2 F[4][2];
#pragma unroll
        for (int q = 0; q < 8; q++) {
            const float4 c0 = *(const float4*)(c_lds + 4 * q);
            float ar = fmaf(c0.x, cq[q], -c0.z * sq[q]);
            float ai = fmaf(c0.y, cq[q],  c0.w * sq[q]);
            float br = fmaf(c0.z, cq[q],  c0.x * sq[q]);
            float bi = fmaf(c0.w, cq[q], -c0.y * sq[q]);
            if (q < 4) {
                const bool hi = (L >> (3 - q)) & 1;
                C2 f; f.re = hi ? br : ar; f.im = hi ? bi : ai;  // column 0
                P = cmul(P, f);
            } else {
                F[q-4][0].re = ar; F[q-4][0].im = ai;
                F[q-4][1].re = br; F[q-4][1].im = bi;
            }
        }
        C2 A0 = cmul(P, F[0][0]), A1 = cmul(P, F[0][1]);
        C2 Bv[4];
        Bv[0] = cmul(A0, F[1][0]); Bv[1] = cmul(A0, F[1][1]);
        Bv[2] = cmul(A1, F[1][0]); Bv[3] = cmul(A1, F[1][1]);
        C2 Cv[8];
#pragma unroll
        for (int i = 0; i < 8; i++) Cv[i] = cmul(Bv[i >> 1], F[2][i & 1]);
#pragma unroll
        for (int t = 0; t < 16; t++) {
            C2 v = cmul(Cv[t >> 1], F[3][t & 1]);
            float m = (t < 8) ? mL : mH;
            m = CZNEG[t] ? -m : m;
            z[t].x = v.re * m;
            z[t].y = v.im * m;
        }
    }

    // ---- transpose: layout A <-> B through LDS (wave-local, no barrier) ----
    auto transpose = [&]() {
        float4* wrow = (float4*)(tb + L * 18);     // row stride 18 slots (144B)
#pragma unroll
        for (int k = 0; k < 8; k++)
            wrow[k] = make_float4(z[2*k].x, z[2*k].y, z[2*k+1].x, z[2*k+1].y);
        __builtin_amdgcn_wave_barrier();
#pragma unroll
        for (int j = 0; j < 16; j++) z[j] = tb[j * 18 + L];
        __builtin_amdgcn_wave_barrier();
    };

    auto cz_A = [&]() {
#pragma unroll
        for (int t = 0; t < 16; t++) {
            v2f m = (t < 8) ? mL2 : mH2;
            z[t] = CZNEG[t] ? pk_mul_neg(m, z[t]) : pk_mul(m, z[t]);
        }
    };
    auto cz_B = [&]() {
#pragma unroll
        for (int j = 0; j < 16; j++) {
            v2f m = (j & 1) ? mO2 : mL2;
            z[j] = CZNEG[j] ? pk_mul_neg(m, z[j]) : pk_mul(m, z[j]);
        }
    };

    // ---------------- layers 1..NL-1 (alternating layouts) -----------------
    v2f arr, aii, brr, bii;
    bool inB = false;
    for (int l = 1; l < NL; l++) {
        const int g0 = l * 8;
        if (!inB) {
            // layout A: wires 4..7 are in-lane (reg bits 3..0)
            build_G(c_lds, g0+4, cq[4], sq[4], arr, aii, brr, bii); su2_inlane<8>(arr, aii, brr, bii, z);
            build_G(c_lds, g0+5, cq[5], sq[5], arr, aii, brr, bii); su2_inlane<4>(arr, aii, brr, bii, z);
            build_G(c_lds, g0+6, cq[6], sq[6], arr, aii, brr, bii); su2_inlane<2>(arr, aii, brr, bii, z);
            build_G(c_lds, g0+7, cq[7], sq[7], arr, aii, brr, bii); su2_inlane<1>(arr, aii, brr, bii, z);
            transpose();
            // layout B: wires 0..3 are in-lane
            build_G(c_lds, g0+0, cq[0], sq[0], arr, aii, brr, bii); su2_inlane<8>(arr, aii, brr, bii, z);
            build_G(c_lds, g0+1, cq[1], sq[1], arr, aii, brr, bii); su2_inlane<4>(arr, aii, brr, bii, z);
            build_G(c_lds, g0+2, cq[2], sq[2], arr, aii, brr, bii); su2_inlane<2>(arr, aii, brr, bii, z);
            build_G(c_lds, g0+3, cq[3], sq[3], arr, aii, brr, bii); su2_inlane<1>(arr, aii, brr, bii, z);
            cz_B();
            inB = true;
        } else {
            build_G(c_lds, g0+0, cq[0], sq[0], arr, aii, brr, bii); su2_inlane<8>(arr, aii, brr, bii, z);
            build_G(c_lds, g0+1, cq[1], sq[1], arr, aii, brr, bii); su2_inlane<4>(arr, aii, brr, bii, z);
            build_G(c_lds, g0+2, cq[2], sq[2], arr, aii, brr, bii); su2_inlane<2>(arr, aii, brr, bii, z);
            build_G(c_lds, g0+3, cq[3], sq[3], arr, aii, brr, bii); su2_inlane<1>(arr, aii, brr, bii, z);
            transpose();
            build_G(c_lds, g0+4, cq[4], sq[4], arr, aii, brr, bii); su2_inlane<8>(arr, aii, brr, bii, z);
            build_G(c_lds, g0+5, cq[5], sq[5], arr, aii, brr, bii); su2_inlane<4>(arr, aii, brr, bii, z);
            build_G(c_lds, g0+6, cq[6], sq[6], arr, aii, brr, bii); su2_inlane<2>(arr, aii, brr, bii, z);
            build_G(c_lds, g0+7, cq[7], sq[7], arr, aii, brr, bii); su2_inlane<1>(arr, aii, brr, bii, z);
            cz_A();
            inB = false;
        }
    }

    // ---------------- final RY layer (all gates commute) -------------------
    {
        v2f cc, ss;
        if (inB) {
            cc=(v2f){cq[0],cq[0]}; ss=(v2f){sq[0],sq[0]}; ry_inlane<8>(cc, ss, z);
            cc=(v2f){cq[1],cq[1]}; ss=(v2f){sq[1],sq[1]}; ry_inlane<4>(cc, ss, z);
            cc=(v2f){cq[2],cq[2]}; ss=(v2f){sq[2],sq[2]}; ry_inlane<2>(cc, ss, z);
            cc=(v2f){cq[3],cq[3]}; ss=(v2f){sq[3],sq[3]}; ry_inlane<1>(cc, ss, z);
            transpose();
            cc=(v2f){cq[4],cq[4]}; ss=(v2f){sq[4],sq[4]}; ry_inlane<8>(cc, ss, z);
            cc=(v2f){cq[5],cq[5]}; ss=(v2f){sq[5],sq[5]}; ry_inlane<4>(cc, ss, z);
            cc=(v2f){cq[6],cq[6]}; ss=(v2f){sq[6],sq[6]}; ry_inlane<2>(cc, ss, z);
            cc=(v2f){cq[7],cq[7]}; ss=(v2f){sq[7],sq[7]}; ry_inlane<1>(cc, ss, z);
            // ends in layout A
        } else {
            cc=(v2f){cq[4],cq[4]}; ss=(v2f){sq[4],sq[4]}; ry_inlane<8>(cc, ss, z);
            cc=(v2f){cq[5],cq[5]}; ss=(v2f){sq[5],sq[5]}; ry_inlane<4>(cc, ss, z);
            cc=(v2f){cq[6],cq[6]}; ss=(v2f){sq[6],sq[6]}; ry_inlane<2>(cc, ss, z);
            cc=(v2f){cq[7],cq[7]}; ss=(v2f){sq[7],sq[7]}; ry_inlane<1>(cc, ss, z);
            transpose();
            cc=(v2f){cq[0],cq[0]}; ss=(v2f){sq[0],sq[0]}; ry_inlane<8>(cc, ss, z);
            cc=(v2f){cq[1],cq[1]}; ss=(v2f){sq[1],sq[1]}; ry_inlane<4>(cc, ss, z);
            cc=(v2f){cq[2],cq[2]}; ss=(v2f){sq[2],sq[2]}; ry_inlane<2>(cc, ss, z);
            cc=(v2f){cq[3],cq[3]}; ss=(v2f){sq[3],sq[3]}; ry_inlane<1>(cc, ss, z);
            transpose();           // back to layout A (only for odd NL)
        }
    }

    // ---------------- probs -> <Z_w> (layout A) ----------------
    float p[16];
#pragma unroll
    for (int t = 0; t < 16; t++) p[t] = fmaf(z[t].x, z[t].x, z[t].y * z[t].y);

    float e0 = p[0]+p[1],  e1 = p[2]+p[3],  e2 = p[4]+p[5],  e3 = p[6]+p[7];
    float e4 = p[8]+p[9],  e5 = p[10]+p[11], e6 = p[12]+p[13], e7 = p[14]+p[15];
    float q0 = e0+e1, q1 = e2+e3, q2 = e4+e5, q3 = e6+e7;
    float h0 = q0+q1, h1 = q2+q3;
    float sumP = h0 + h1;

    float zv[8];
#pragma unroll
    for (int w = 0; w < 4; w++)
        zv[w] = ((L >> (3 - w)) & 1) ? -sumP : sumP;
    zv[4] = h0 - h1;
    zv[5] = (q0 - q1) + (q2 - q3);
    zv[6] = (e0 - e1) + (e2 - e3) + (e4 - e5) + (e6 - e7);
    zv[7] = (p[0]-p[1]) + (p[2]-p[3]) + (p[4]-p[5]) + (p[6]-p[7])
          + (p[8]-p[9]) + (p[10]-p[11]) + (p[12]-p[13]) + (p[14]-p[15]);

#pragma unroll
    for (int w = 0; w < 8; w++) zv[w] += lxor<1>(zv[w]);
#pragma unroll
    for (int w = 0; w < 8; w++) zv[w] += lxor<2>(zv[w]);
#pragma unroll
    for (int w = 0; w < 8; w++) zv[w] += lxor<4>(zv[w]);
#pragma unroll
    for (int w = 0; w < 8; w++) zv[w] += lxor<8>(zv[w]);

    // ---------------- decoder MLP ----------------
    float h2[8];
#pragma unroll
    for (int j = 0; j < 8; j++) {
        float a = db1[j];
#pragma unroll
        for (int w = 0; w < 8; w++) a = fmaf(dw1[j * 8 + w], zv[w], a);
        h2[j] = fmaxf(a, 0.0f);
    }
    if (L < 4) {
        float a = db2[L];
#pragma unroll
        for (int j = 0; j < 8; j++) a = fmaf(dw2[L * 8 + j], h2[j], a);
        out[s * 4 + L] = a;
    }
}

extern "C" void kernel_launch(void* const* d_in, const int* in_sizes, int n_in,
                              void* d_out, int out_size, void* d_ws, size_t ws_size,
                              hipStream_t stream) {
    const float* x   = (const float*)d_in[0];
    const float* ew1 = (const float*)d_in[1];
    const float* eb1 = (const float*)d_in[2];
    const float* ew2 = (const float*)d_in[3];
    const float* eb2 = (const float*)d_in[4];
    const float* qw  = (const float*)d_in[5];
    const float* dw1 = (const float*)d_in[6];
    const float* db1 = (const float*)d_in[7];
    const float* dw2 = (const float*)d_in[8];
    const float* db2 = (const float*)d_in[9];
    float* out = (float*)d_out;

    int B = in_sizes[0] / 16;        // 32768
    int n_gates = in_sizes[5] / 3;   // 32
    int NL = n_gates / 8;            // 4

    // 8 samples per 128-thread block (2 waves x 4 samples/wave)
    int blocks = (B + 7) / 8;
    qdqn_kernel<<<blocks, 128, 0, stream>>>(x, ew1, eb1, ew2, eb2, qw,
                                            dw1, db1, dw2, db2, out, B, NL);
}